// Round 17
// baseline (97.726 us; speedup 1.0000x reference)
//
#include <hip/hip_runtime.h>
#include <hip/hip_bf16.h>

// Problem dims: x[b=8, c=64, h=64, w=64, t=12] fp32
// x float offsets: b*3145728 + c*49152 + h*768 + w*12 + t
//
// Scratch inside d_out (floats), consumed before k_out overwrites d_out:
//   [4096, 4096+10*393216) : u[chalf*5+dh][m*12+t]  (10 planes, 15.7 MB)
#define U_OFF    4096
#define U_PLANE  393216   // floats per plane
// d_ws: p[m*12+t] (1.57 MB) + weff[c*25+tap] at float offset 393216
#define WS_WEFF_OFF 393216
#define WEFF_FALLBACK_OFF 0   // in d_out if ws too small

// ---------------------------------------------------------------------------
// K1: fold 1x1-conv (key half of w1) into the 5x5 conv weights.
__global__ __launch_bounds__(256) void k_prep(const float* __restrict__ w1,
                                              const float* __restrict__ w2,
                                              float* __restrict__ wdst) {
    int idx = blockIdx.x * 256 + threadIdx.x;
    if (idx >= 64 * 25) return;
    int cp = idx / 25, tap = idx % 25;
    float s = 0.f;
    for (int c = 0; c < 64; ++c)
        s = fmaf(w2[(64 + c) * 25 + tap], w1[(64 + c) * 64 + cp], s);
    wdst[cp * 25 + tap] = s;
}

// ---------------------------------------------------------------------------
// K2a (k_tap, c-split x2): tests the last standing theory — the per-thread
// 64-step c-chain is effectively serial, so halving it should ~halve the
// 56us wall. Thread per (m,t,chalf): 3072 blocks x 256 thr (32 waves/CU
// resident); each thread contracts 32 channels into 5 dh-accumulators and
// writes partial planes u[chalf*5+dh]. Everything else identical to R16's
// proven dh-factored kernel (same loads, same wave-uniform weights).
__global__ __launch_bounds__(256) void k_tap(const float* __restrict__ x,
                                             const float* __restrict__ weff,
                                             float* __restrict__ u) {
    const int chalf = (blockIdx.x >= 1536) ? 1 : 0;
    const int gid   = (blockIdx.x - chalf * 1536) * 256 + threadIdx.x; // 0..393215
    const int m   = gid / 12;
    const int t   = gid - m * 12;
    const int w   = m & 63;
    const int h   = (m >> 6) & 63;
    const int b   = m >> 12;

    const float* xp = x + (size_t)b * 3145728 + h * 768 + w * 12 + t
                        + (size_t)(chalf * 32) * 49152;

    // edge predicates + clamped offsets (no OOB addresses formed)
    const bool ok0 = (w >= 2), ok1 = (w >= 1), ok3 = (w <= 62), ok4 = (w <= 61);
    const int  o0 = ok0 ? -24 : 0, o1 = ok1 ? -12 : 0;
    const int  o3 = ok3 ?  12 : 0, o4 = ok4 ?  24 : 0;

    float u0 = 0.f, u1 = 0.f, u2 = 0.f, u3 = 0.f, u4 = 0.f;

    const float* wbase = weff + chalf * 32 * 25;
    for (int cb = 0; cb < 8; ++cb) {
        float xv[4][5];
#pragma unroll
        for (int j = 0; j < 4; ++j) {
            const float* base = xp + (size_t)(cb * 4 + j) * 49152;
            float v0 = base[o0], v1 = base[o1], v2 = base[0];
            float v3 = base[o3], v4 = base[o4];
            xv[j][0] = ok0 ? v0 : 0.f;
            xv[j][1] = ok1 ? v1 : 0.f;
            xv[j][2] = v2;
            xv[j][3] = ok3 ? v3 : 0.f;
            xv[j][4] = ok4 ? v4 : 0.f;
        }
#pragma unroll
        for (int j = 0; j < 4; ++j) {
            const float* wg = wbase + (cb * 4 + j) * 25;   // wave-uniform -> s_load
#pragma unroll
            for (int dw = 0; dw < 5; ++dw) {
                const float v = xv[j][dw];
                u0 = fmaf(wg[0 * 5 + dw], v, u0);
                u1 = fmaf(wg[1 * 5 + dw], v, u1);
                u2 = fmaf(wg[2 * 5 + dw], v, u2);
                u3 = fmaf(wg[3 * 5 + dw], v, u3);
                u4 = fmaf(wg[4 * 5 + dw], v, u4);
            }
        }
    }

    float* ub = u + (size_t)(chalf * 5) * U_PLANE + gid;
    ub[(size_t)0 * U_PLANE] = u0;
    ub[(size_t)1 * U_PLANE] = u1;
    ub[(size_t)2 * U_PLANE] = u2;
    ub[(size_t)3 * U_PLANE] = u3;
    ub[(size_t)4 * U_PLANE] = u4;
}

// ---------------------------------------------------------------------------
// K2b (k_gather, 10-plane): A_k[m,t] = sum_{chalf,dh} u[chalf*5+dh][b,h+dh-2,w,t]
// (OOB dh skipped == zero-pad), softmax over t, write p. u is L2/L3-resident.
__global__ __launch_bounds__(256) void k_gather(const float* __restrict__ u,
                                                float* __restrict__ p) {
    const int tid  = threadIdx.x;
    const int m    = blockIdx.x * 64 + (tid >> 2);   // 0..32767
    const int q    = tid & 3;
    const int qq   = (q == 3) ? 2 : q;
    const int w    = m & 63;
    const int h    = (m >> 6) & 63;
    const int b    = m >> 12;

    float4 a; a.x = 0.f; a.y = 0.f; a.z = 0.f; a.w = 0.f;

#pragma unroll
    for (int dh = 0; dh < 5; ++dh) {
        const int hh = h + dh - 2;
        if ((unsigned)hh >= 64u) continue;           // block-uniform skip
        const size_t moff = (size_t)(((b * 64 + hh) * 64 + w)) * 12 + qq * 4;
        const float* up0 = u + (size_t)dh * U_PLANE + moff;
        const float* up1 = u + (size_t)(5 + dh) * U_PLANE + moff;
        float4 v0 = *(const float4*)(up0);
        float4 v1 = *(const float4*)(up1);
        a.x += v0.x + v1.x; a.y += v0.y + v1.y;
        a.z += v0.z + v1.z; a.w += v0.w + v1.w;
    }

    float mx = fmaxf(fmaxf(a.x, a.y), fmaxf(a.z, a.w));
    mx = fmaxf(mx, __shfl_xor(mx, 1, 4));
    mx = fmaxf(mx, __shfl_xor(mx, 2, 4));

    float e0 = __expf(a.x - mx), e1 = __expf(a.y - mx);
    float e2 = __expf(a.z - mx), e3 = __expf(a.w - mx);
    const float s4 = e0 + e1 + e2 + e3;
    const float s0 = __shfl(s4, 0, 4);
    const float s1 = __shfl(s4, 1, 4);
    const float s2 = __shfl(s4, 2, 4);
    const float inv = 1.f / (s0 + s1 + s2);

    if (q < 3) {
        float4 o; o.x = e0 * inv; o.y = e1 * inv; o.z = e2 * inv; o.w = e3 * inv;
        *(float4*)(p + (size_t)m * 12 + q * 4) = o;
    }
}

// ---------------------------------------------------------------------------
// K4: out[b,c,h,w,s] = W1v · (sum_t p_t * x[:,t]) + b1v, broadcast over s.
// One block per (b,h): 512 threads = 64 w-lanes * 8 channel-groups.
// Proven ~34 us (near its 200MB roofline).
__global__ __launch_bounds__(512) void k_out(const float* __restrict__ x,
                                             const float* __restrict__ w1,
                                             const float* __restrict__ b1,
                                             const float* __restrict__ p,
                                             float* __restrict__ out) {
    __shared__ float lds[64 * 65];   // [w][c], padded -> conflict-free

    const int b  = blockIdx.x >> 6;
    const int h  = blockIdx.x & 63;
    const int w  = threadIdx.x & 63;
    const int cg = threadIdx.x >> 6;     // 0..7

    const float* pp = p + (size_t)((b * 64 + h) * 64 + w) * 12;
    float pv[12];
    {
        float4 t0 = *(const float4*)(pp);
        float4 t1 = *(const float4*)(pp + 4);
        float4 t2 = *(const float4*)(pp + 8);
        pv[0] = t0.x; pv[1] = t0.y; pv[2]  = t0.z; pv[3]  = t0.w;
        pv[4] = t1.x; pv[5] = t1.y; pv[6]  = t1.z; pv[7]  = t1.w;
        pv[8] = t2.x; pv[9] = t2.y; pv[10] = t2.z; pv[11] = t2.w;
    }

    const float* xb0 = x + ((size_t)(b * 64 + cg * 8) * 64 + h) * 768 + w * 12;
#pragma unroll
    for (int j = 0; j < 8; ++j) {
        const float* xp = xb0 + (size_t)j * 49152;
        float4 u0 = *(const float4*)(xp);
        float4 u1 = *(const float4*)(xp + 4);
        float4 u2 = *(const float4*)(xp + 8);
        float s = 0.f;
        s = fmaf(pv[0], u0.x, s);  s = fmaf(pv[1], u0.y, s);
        s = fmaf(pv[2], u0.z, s);  s = fmaf(pv[3], u0.w, s);
        s = fmaf(pv[4], u1.x, s);  s = fmaf(pv[5], u1.y, s);
        s = fmaf(pv[6], u1.z, s);  s = fmaf(pv[7], u1.w, s);
        s = fmaf(pv[8], u2.x, s);  s = fmaf(pv[9], u2.y, s);
        s = fmaf(pv[10], u2.z, s); s = fmaf(pv[11], u2.w, s);
        lds[w * 65 + cg * 8 + j] = s;
    }
    __syncthreads();

    const float* w1v = w1 + 128 * 64 + cg * 8 * 64;
    float acc[8];
#pragma unroll
    for (int j = 0; j < 8; ++j) acc[j] = b1[128 + cg * 8 + j];
    for (int c2 = 0; c2 < 64; ++c2) {
        const float xv = lds[w * 65 + c2];
#pragma unroll
        for (int j = 0; j < 8; ++j)
            acc[j] = fmaf(w1v[j * 64 + c2], xv, acc[j]);
    }

#pragma unroll
    for (int j = 0; j < 8; ++j) {
        const int co = cg * 8 + j;
        float4 f; f.x = acc[j]; f.y = acc[j]; f.z = acc[j]; f.w = acc[j];
        float* op = out + ((size_t)(b * 64 + co) * 4096 + h * 64 + w) * 12;
        *(float4*)(op)     = f;
        *(float4*)(op + 4) = f;
        *(float4*)(op + 8) = f;
    }
}

// ---------------------------------------------------------------------------
extern "C" void kernel_launch(void* const* d_in, const int* in_sizes, int n_in,
                              void* d_out, int out_size, void* d_ws, size_t ws_size,
                              hipStream_t stream) {
    const float* x  = (const float*)d_in[0];
    const float* w1 = (const float*)d_in[1];
    const float* b1 = (const float*)d_in[2];
    const float* w2 = (const float*)d_in[3];
    // d_in[4] = b2: constant across the softmax axis -> cancels, unused.

    float* outp = (float*)d_out;
    float* u    = outp + U_OFF;      // 15.7 MB partial planes (scratch in d_out)
    float* p    = (float*)d_ws;      // 1.57 MB

    const bool ws_fits = ws_size >= (size_t)(WS_WEFF_OFF + 1600) * sizeof(float);
    float* weff = ws_fits ? (p + WS_WEFF_OFF) : (outp + WEFF_FALLBACK_OFF);

    hipLaunchKernelGGL(k_prep,   dim3(7),    dim3(256), 0, stream, w1, w2, weff);
    hipLaunchKernelGGL(k_tap,    dim3(3072), dim3(256), 0, stream, x, weff, u);
    hipLaunchKernelGGL(k_gather, dim3(512),  dim3(256), 0, stream, u, p);
    hipLaunchKernelGGL(k_out,    dim3(512),  dim3(512), 0, stream, x, w1, b1, p, outp);
}